// Round 1
// baseline (2795.491 us; speedup 1.0000x reference)
//
#include <hip/hip_runtime.h>
#include <hip/hip_bf16.h>
#include <cstdint>
#include <cstddef>

// ---------------- problem constants ----------------
#define NUQ 20000
#define NIQ 30000
#define NNQ 50000
#define NNZ_ADJQ 1000000
#define NNZ_IIQ  600000
#define NNZ_UUQ  400000

// ---------------- wave helpers (wave64) ----------------
static __device__ __forceinline__ float wredsum(float v){
#pragma unroll
  for (int m = 32; m; m >>= 1) v += __shfl_xor(v, m);
  return v;
}

// ---------------- misc elementwise kernels ----------------
__global__ __launch_bounds__(256) void zero_k(float* p, int n){
  int i = blockIdx.x * 256 + threadIdx.x;
  if (i < n) p[i] = 0.f;
}
__global__ __launch_bounds__(256) void izero_k(int* p, int n){
  int i = blockIdx.x * 256 + threadIdx.x;
  if (i < n) p[i] = 0;
}
// copy 64 leading cols of src (stride lds_) into dst (stride ldd)
__global__ __launch_bounds__(256) void copy64_k(const float* __restrict__ src, int lds_,
                                                float* __restrict__ dst, int ldd, int n){
  int i = blockIdx.x * 256 + threadIdx.x;
  if (i >= n * 64) return;
  int r = i >> 6, d = i & 63;
  dst[(size_t)r * ldd + d] = src[(size_t)r * lds_ + d];
}
__global__ __launch_bounds__(256) void mean3_k(const float* __restrict__ a,
                                               const float* __restrict__ b,
                                               const float* __restrict__ c,
                                               float* __restrict__ o, int n){
  int i = blockIdx.x * 256 + threadIdx.x;
  if (i < n) o[i] = (a[i] + b[i] + c[i]) * (1.f / 3.f);
}
// user part of ego_feat: prelu of user_prop cols [64:192) -> ego cols [0:128)
__global__ __launch_bounds__(256) void ego_user_k(const float* __restrict__ up,
                                                  const float* __restrict__ alphaP,
                                                  float* __restrict__ egoF, int n){
  int i = blockIdx.x * 256 + threadIdx.x;
  if (i >= n * 64) return;
  int r = i >> 6, d = i & 63;
  float a = alphaP[0];
  float v = up[(size_t)r * 192 + 64 + d];
  float t = up[(size_t)r * 192 + 128 + d];
  egoF[(size_t)r * 128 + d]      = v >= 0.f ? v : a * v;
  egoF[(size_t)r * 128 + 64 + d] = t >= 0.f ? t : a * t;
}

// ---------------- CSR build ----------------
__global__ __launch_bounds__(256) void count_k(const int* __restrict__ row, int nnz, int* cnt){
  int i = blockIdx.x * 256 + threadIdx.x;
  if (i < nnz) atomicAdd(&cnt[row[i]], 1);
}
// inclusive scan of 1024-elem chunks (256 thr x 4), emits block sums
__global__ __launch_bounds__(256) void scan_chunk(int* d, int n, int* bsums){
  int base = blockIdx.x * 1024 + threadIdx.x * 4;
  int a0 = (base + 0 < n) ? d[base + 0] : 0;
  int a1 = (base + 1 < n) ? d[base + 1] : 0;
  int a2 = (base + 2 < n) ? d[base + 2] : 0;
  int a3 = (base + 3 < n) ? d[base + 3] : 0;
  int s1 = a0 + a1, s2 = s1 + a2, s3 = s2 + a3;
  int tsum = s3;
  int lane = threadIdx.x & 63, w = threadIdx.x >> 6;
  int sc = tsum;
#pragma unroll
  for (int off = 1; off < 64; off <<= 1){
    int t = __shfl_up(sc, off);
    if (lane >= off) sc += t;
  }
  __shared__ int wsm[4];
  if (lane == 63) wsm[w] = sc;
  __syncthreads();
  int woff = 0;
#pragma unroll
  for (int i = 0; i < 4; i++) if (i < w) woff += wsm[i];
  int excl = woff + sc - tsum;
  if (base + 0 < n) d[base + 0] = excl + a0;
  if (base + 1 < n) d[base + 1] = excl + s1;
  if (base + 2 < n) d[base + 2] = excl + s2;
  if (base + 3 < n) d[base + 3] = excl + s3;
  if (threadIdx.x == 255) bsums[blockIdx.x] = wsm[0] + wsm[1] + wsm[2] + wsm[3];
}
// exclusive scan of <=64 block sums, single wave
__global__ void scan_tops(int* bsums, int nb){
  int lane = threadIdx.x;
  int v = (lane < nb) ? bsums[lane] : 0;
  int sc = v;
#pragma unroll
  for (int off = 1; off < 64; off <<= 1){
    int t = __shfl_up(sc, off);
    if (lane >= off) sc += t;
  }
  if (lane < nb) bsums[lane] = sc - v;
}
__global__ __launch_bounds__(256) void scan_add(int* d, int n, const int* bsums){
  int base = blockIdx.x * 1024 + threadIdx.x * 4;
  int off = bsums[blockIdx.x];
#pragma unroll
  for (int e = 0; e < 4; e++) if (base + e < n) d[base + e] += off;
}
__global__ __launch_bounds__(256) void copyi_k(const int* s, int* dd, int n){
  int i = blockIdx.x * 256 + threadIdx.x;
  if (i < n) dd[i] = s[i];
}
__global__ __launch_bounds__(256) void fill_k(const int* __restrict__ row, const int* __restrict__ col,
                                              const float* __restrict__ val, int nnz,
                                              int* cur, int* __restrict__ ccol, float* __restrict__ cval){
  int i = blockIdx.x * 256 + threadIdx.x;
  if (i < nnz){
    int r = row[i];
    int p = atomicAdd(&cur[r], 1);
    ccol[p] = col[i];
    cval[p] = val[i];
  }
}

// ---------------- SpMM (wave per row, gather, optional fused row-l2norm) ----------------
template<int DIMV>  // dim = 64*DIMV
__global__ __launch_bounds__(256) void spmm_k(const int* __restrict__ ptr, const int* __restrict__ cidx,
                                              const float* __restrict__ cval, const float* __restrict__ X,
                                              float* __restrict__ out, int nRows, int doNorm){
  int wid = (blockIdx.x * 256 + threadIdx.x) >> 6;
  int lane = threadIdx.x & 63;
  if (wid >= nRows) return;
  int e0 = ptr[wid], e1 = ptr[wid + 1];
  float a0 = 0.f, a1 = 0.f, a2 = 0.f;
  constexpr int DIM = DIMV * 64;
  for (int e = e0; e < e1; e++){
    int c = cidx[e];
    float v = cval[e];
    const float* xr = X + (size_t)c * DIM;
    if (DIMV == 1){
      a0 = fmaf(v, xr[lane], a0);
    } else {
      float2 t = *reinterpret_cast<const float2*>(xr + lane * 2);
      a0 = fmaf(v, t.x, a0);
      a1 = fmaf(v, t.y, a1);
      if (DIMV == 3) a2 = fmaf(v, xr[128 + lane], a2);
    }
  }
  if (doNorm){
    float ss = a0 * a0 + a1 * a1 + a2 * a2;
    ss = wredsum(ss);
    float sc = 1.f / fmaxf(sqrtf(ss), 1e-12f);
    a0 *= sc; a1 *= sc; a2 *= sc;
  }
  float* orow = out + (size_t)wid * DIM;
  if (DIMV == 1){
    orow[lane] = a0;
  } else {
    *reinterpret_cast<float2*>(orow + lane * 2) = make_float2(a0, a1);
    if (DIMV == 3) orow[128 + lane] = a2;
  }
}

// ---------------- tiny-attn + LayerNorm + PReLU fused (wave per row) ----------------
__global__ __launch_bounds__(256) void attn_k(const float* __restrict__ xq, int ldq,
                                              const float* __restrict__ xkv, int ldkv,
                                              const float* __restrict__ basep, int ldb,
                                              const float* __restrict__ aw, const float* __restrict__ ab, int idx,
                                              const float* __restrict__ aow, const float* __restrict__ aob,
                                              const float* __restrict__ gamma, const float* __restrict__ beta,
                                              const float* __restrict__ alphaP,
                                              float* __restrict__ out, int ldo, int nRows){
  int wid = (blockIdx.x * 256 + threadIdx.x) >> 6;
  int lane = threadIdx.x & 63;
  if (wid >= nRows) return;
  float w0 = aw[idx * 3 + 0], w1 = aw[idx * 3 + 1], w2 = aw[idx * 3 + 2];
  float b0 = ab[idx * 3 + 0], b1 = ab[idx * 3 + 1], b2 = ab[idx * 3 + 2];
  float wo = aow[idx], bo = aob[idx];
  float q  = xq [(size_t)wid * ldq  + lane] * w0 + b0;
  float kv = xkv[(size_t)wid * ldkv + lane];
  float k = kv * w1 + b1, v = kv * w2 + b2;
  float kmx = k, kmn = k;
#pragma unroll
  for (int m = 32; m; m >>= 1){
    kmx = fmaxf(kmx, __shfl_xor(kmx, m));
    kmn = fminf(kmn, __shfl_xor(kmn, m));
  }
  float mx = (q >= 0.f) ? q * kmx : q * kmn;   // exact rowwise softmax max for rank-1 logits
  float se = 0.f, sv = 0.f;
  for (int m = 0; m < 64; m++){
    float km = __shfl(k, m), vm = __shfl(v, m);
    float e = __expf(fmaf(q, km, -mx));
    se += e;
    sv = fmaf(e, vm, sv);
  }
  float o = (sv / se) * wo + bo;
  float y = basep[(size_t)wid * ldb + lane] + o;
  float mu = wredsum(y) * (1.f / 64.f);
  float dd = y - mu;
  float var = wredsum(dd * dd) * (1.f / 64.f);
  float z = dd * rsqrtf(var + 1e-5f) * gamma[lane] + beta[lane];
  float a = alphaP[0];
  out[(size_t)wid * ldo + lane] = z >= 0.f ? z : a * z;
}

// ---------------- GEMM: out = X @ W^T + B, 256 thr, 8x8 per thread ----------------
// TN in {64,256}, TM = 16384/TN. Swizzled LDS (bank-conflict-free b128 reads).
// Two row-groups (user/item) with separate W/B selected by blockIdx.x < uBlocks.
// EPI: 0 store+bias, 1 atomicAdd (+bias only on k-slice 0), 2 prelu, 3 rowwise l2norm (needs TN==256)
template<int TN, int EPI>
__global__ __launch_bounds__(256)
void gemm_k(const float* __restrict__ X, int ldx, int Mtot,
            const float* __restrict__ Wu, const float* __restrict__ Wi,
            const float* __restrict__ Bu, const float* __restrict__ Bi,
            float* __restrict__ outp, int ldo,
            int K, int kSlice,
            int uBlocks, int uEnd,
            const float* __restrict__ alphaPtr, int aU, int aI){
  constexpr int TM = 16384 / TN;
  constexpr int KC = 32;
  constexpr int SX = (TM == 256) ? 284 : 68;   // TM + 4*(TM/8-1)/4 rounded; monotone swizzle pad
  constexpr int SW = (TN == 64)  ? 68  : 268;
  static_assert(TM * TN == 16384, "tile");
  __shared__ float lx[KC * SX];
  __shared__ float lw[KC * SW];

  const int tid = threadIdx.x;
  const int bx = blockIdx.x;
  const bool isU = bx < uBlocks;
  const int rowBase = isU ? bx * TM : uEnd + (bx - uBlocks) * TM;
  const int groupEnd = isU ? uEnd : Mtot;
  const float* Wt = isU ? Wu : Wi;
  const float* Bs = isU ? Bu : Bi;

  const int kBeg = blockIdx.y * kSlice;
  const int kEnd = min(K, kBeg + kSlice);

  constexpr int CGN = TN / 8;
  const int cg = tid % CGN;
  const int rg = tid / CGN;

  float acc[8][8];
#pragma unroll
  for (int i = 0; i < 8; i++)
#pragma unroll
    for (int j = 0; j < 8; j++) acc[i][j] = 0.f;

  const int xoff = 8 * rg + 4 * (rg >> 2);
  const int woff = (TN == 64) ? (8 * cg + 4 * (cg >> 2)) : (8 * cg + 4 * (cg >> 3));

  for (int k0 = kBeg; k0 < kEnd; k0 += KC){
    { // stage X tile (TM x 32), transposed + swizzled
      constexpr int NF = TM * KC / 4;
#pragma unroll
      for (int f = tid; f < NF; f += 256){
        int row = f >> 3;
        int kq = f & 7;
        int grow = rowBase + row;
        float4 v = make_float4(0.f, 0.f, 0.f, 0.f);
        if (grow < groupEnd)
          v = *reinterpret_cast<const float4*>(X + (size_t)grow * ldx + k0 + kq * 4);
        int g = row >> 3, ri = row & 7;
        int pos = 8 * g + 4 * (g >> 2) + ri;
        int kb = kq * 4;
        lx[(kb + 0) * SX + pos] = v.x;
        lx[(kb + 1) * SX + pos] = v.y;
        lx[(kb + 2) * SX + pos] = v.z;
        lx[(kb + 3) * SX + pos] = v.w;
      }
    }
    { // stage W tile (TN x 32)
      constexpr int NF = TN * KC / 4;
#pragma unroll
      for (int f = tid; f < NF; f += 256){
        int c = f >> 3;
        int kq = f & 7;
        float4 v = *reinterpret_cast<const float4*>(Wt + (size_t)c * K + k0 + kq * 4);
        int g = c >> 3, ci = c & 7;
        int pos = (TN == 64) ? (8 * g + 4 * (g >> 2) + ci) : (8 * g + 4 * (g >> 3) + ci);
        int kb = kq * 4;
        lw[(kb + 0) * SW + pos] = v.x;
        lw[(kb + 1) * SW + pos] = v.y;
        lw[(kb + 2) * SW + pos] = v.z;
        lw[(kb + 3) * SW + pos] = v.w;
      }
    }
    __syncthreads();
#pragma unroll 4
    for (int kk = 0; kk < KC; kk++){
      const float4 a0 = *reinterpret_cast<const float4*>(&lx[kk * SX + xoff]);
      const float4 a1 = *reinterpret_cast<const float4*>(&lx[kk * SX + xoff + 4]);
      const float4 b0 = *reinterpret_cast<const float4*>(&lw[kk * SW + woff]);
      const float4 b1 = *reinterpret_cast<const float4*>(&lw[kk * SW + woff + 4]);
      float av[8] = {a0.x, a0.y, a0.z, a0.w, a1.x, a1.y, a1.z, a1.w};
      float bv[8] = {b0.x, b0.y, b0.z, b0.w, b1.x, b1.y, b1.z, b1.w};
#pragma unroll
      for (int i = 0; i < 8; i++)
#pragma unroll
        for (int j = 0; j < 8; j++)
          acc[i][j] = fmaf(av[i], bv[j], acc[i][j]);
    }
    __syncthreads();
  }

  float bias[8];
#pragma unroll
  for (int j = 0; j < 8; j++) bias[j] = Bs[cg * 8 + j];

  if constexpr (EPI == 3){ // rowwise l2norm over TN==256 cols (full row in block)
    __shared__ float lred[64][33];
    __shared__ float lscale[64];
#pragma unroll
    for (int i = 0; i < 8; i++){
      float p = 0.f;
#pragma unroll
      for (int j = 0; j < 8; j++){
        float y = acc[i][j] + bias[j];
        p += y * y;
      }
      lred[rg * 8 + i][cg] = p;
    }
    __syncthreads();
    if (tid < 64){
      float s = 0.f;
#pragma unroll
      for (int c = 0; c < 32; c++) s += lred[tid][c];
      lscale[tid] = 1.f / fmaxf(sqrtf(s), 1e-12f);
    }
    __syncthreads();
#pragma unroll
    for (int i = 0; i < 8; i++){
      int row = rowBase + rg * 8 + i;
      if (row < groupEnd){
        float sc = lscale[rg * 8 + i];
        float* op = outp + (size_t)row * ldo + cg * 8;
        float4 o0 = make_float4((acc[i][0] + bias[0]) * sc, (acc[i][1] + bias[1]) * sc,
                                (acc[i][2] + bias[2]) * sc, (acc[i][3] + bias[3]) * sc);
        float4 o1 = make_float4((acc[i][4] + bias[4]) * sc, (acc[i][5] + bias[5]) * sc,
                                (acc[i][6] + bias[6]) * sc, (acc[i][7] + bias[7]) * sc);
        *reinterpret_cast<float4*>(op) = o0;
        *reinterpret_cast<float4*>(op + 4) = o1;
      }
    }
  } else {
    float alpha = 0.f;
    if constexpr (EPI == 2) alpha = alphaPtr[isU ? aU : aI];
    bool addBias = (EPI != 1) || (blockIdx.y == 0);
#pragma unroll
    for (int i = 0; i < 8; i++){
      int row = rowBase + rg * 8 + i;
      if (row < groupEnd){
        float* op = outp + (size_t)row * ldo + cg * 8;
        if constexpr (EPI == 1){
#pragma unroll
          for (int j = 0; j < 8; j++)
            atomicAdd(op + j, acc[i][j] + (addBias ? bias[j] : 0.f));
        } else {
          float vv[8];
#pragma unroll
          for (int j = 0; j < 8; j++){
            float y = acc[i][j] + bias[j];
            if constexpr (EPI == 2) y = (y >= 0.f) ? y : alpha * y;
            vv[j] = y;
          }
          *reinterpret_cast<float4*>(op)     = make_float4(vv[0], vv[1], vv[2], vv[3]);
          *reinterpret_cast<float4*>(op + 4) = make_float4(vv[4], vv[5], vv[6], vv[7]);
        }
      }
    }
  }
}

// ---------------- final: share einsums + assemble output (wave per row) ----------------
__global__ __launch_bounds__(256) void final_k(const float* __restrict__ finFeat,
                                               const float* __restrict__ finId,
                                               const float* __restrict__ m1,
                                               const float* __restrict__ m2,
                                               const float* __restrict__ alphaP,
                                               float* __restrict__ out, int nRows){
  int wid = (blockIdx.x * 256 + threadIdx.x) >> 6;
  int lane = threadIdx.x & 63;
  if (wid >= nRows) return;
  float a = alphaP[0];
  float idv = finId[(size_t)wid * 64 + lane];
  float4 m1v = *reinterpret_cast<const float4*>(m1 + (size_t)wid * 256 + lane * 4);
  float t0 = idv * m1v.x, t1 = idv * m1v.y, t2 = idv * m1v.z, t3 = idv * m1v.w;
#pragma unroll
  for (int m = 32; m; m >>= 1){
    t0 += __shfl_xor(t0, m);
    t1 += __shfl_xor(t1, m);
    t2 += __shfl_xor(t2, m);
    t3 += __shfl_xor(t3, m);
  }
  const float* m2r = m2 + (size_t)wid * 256;
  float sh = t0 * m2r[lane] + t1 * m2r[64 + lane] + t2 * m2r[128 + lane] + t3 * m2r[192 + lane];
  float fv = finFeat[(size_t)wid * 128 + lane];
  float ft = finFeat[(size_t)wid * 128 + 64 + lane];
  fv = ((fv >= 0.f) ? fv : a * fv) + idv;
  ft = ((ft >= 0.f) ? ft : a * ft) + idv;
  sh = ((sh >= 0.f) ? sh : a * sh) + idv;
  float* orow = out + (size_t)wid * 192;
  orow[lane] = fv;
  orow[64 + lane] = ft;
  orow[128 + lane] = sh;
}

// ---------------- host launcher ----------------
extern "C" void kernel_launch(void* const* d_in, const int* in_sizes, int n_in,
                              void* d_out, int out_size, void* d_ws, size_t ws_size,
                              hipStream_t stream){
  const float* user_id_emb  = (const float*)d_in[0];
  const float* item_id_emb  = (const float*)d_in[1];
  const float* image_feat   = (const float*)d_in[2];
  const float* text_feat    = (const float*)d_in[3];
  const float* user_v_pref  = (const float*)d_in[4];
  const float* user_t_pref  = (const float*)d_in[5];
  const float* img_i_w = (const float*)d_in[6];
  const float* img_i_b = (const float*)d_in[7];
  const float* txt_i_w = (const float*)d_in[8];
  const float* txt_i_b = (const float*)d_in[9];
  const float* img_u_w = (const float*)d_in[10];
  const float* img_u_b = (const float*)d_in[11];
  const float* txt_u_w = (const float*)d_in[12];
  const float* txt_u_b = (const float*)d_in[13];
  const float* ln_gamma = (const float*)d_in[14];
  const float* ln_beta  = (const float*)d_in[15];
  const float* prl_alpha = (const float*)d_in[16];
  const float* attn_in_w = (const float*)d_in[17];
  const float* attn_in_b = (const float*)d_in[18];
  const float* attn_out_w = (const float*)d_in[19];
  const float* attn_out_b = (const float*)d_in[20];
  const float* mlp_pre_w = (const float*)d_in[21];
  const float* mlp_pre_b = (const float*)d_in[22];
  const float* mlp_out_w = (const float*)d_in[23];
  const float* mlp_out_b = (const float*)d_in[24];
  const float* mlp_alpha = (const float*)d_in[25];
  const float* meta_u_w = (const float*)d_in[26];
  const float* meta_u_b = (const float*)d_in[27];
  const float* meta_i_w = (const float*)d_in[28];
  const float* meta_i_b = (const float*)d_in[29];
  const float* adj_val = (const float*)d_in[30];
  const float* ii_val  = (const float*)d_in[31];
  const float* uu_val  = (const float*)d_in[32];
  const int* adj_row = (const int*)d_in[33];
  const int* adj_col = (const int*)d_in[34];
  const int* ii_row = (const int*)d_in[35];
  const int* ii_col = (const int*)d_in[36];
  const int* uu_row = (const int*)d_in[37];
  const int* uu_col = (const int*)d_in[38];
  float* out = (float*)d_out;

  // ---- workspace layout (~222 MB, lifetimes hand-checked) ----
  char* ws = (char*)d_ws;
  size_t off = 0;
  auto alloc = [&](size_t bytes){ size_t r = off; off += (bytes + 511) & ~(size_t)511; return r; };
  int*   adjP  = (int*)(ws + alloc((size_t)(NNQ + 1) * 4));
  int*   adjC  = (int*)(ws + alloc((size_t)NNQ * 4));
  int*   adjCol= (int*)(ws + alloc((size_t)NNZ_ADJQ * 4));
  float* adjVal= (float*)(ws + alloc((size_t)NNZ_ADJQ * 4));
  int*   iiP   = (int*)(ws + alloc((size_t)(NIQ + 1) * 4));
  int*   iiC   = (int*)(ws + alloc((size_t)NIQ * 4));
  int*   iiColA= (int*)(ws + alloc((size_t)NNZ_IIQ * 4));
  float* iiValA= (float*)(ws + alloc((size_t)NNZ_IIQ * 4));
  int*   uuP   = (int*)(ws + alloc((size_t)(NUQ + 1) * 4));
  int*   uuC   = (int*)(ws + alloc((size_t)NUQ * 4));
  int*   uuColA= (int*)(ws + alloc((size_t)NNZ_UUQ * 4));
  float* uuValA= (float*)(ws + alloc((size_t)NNZ_UUQ * 4));
  int*   bsums = (int*)(ws + alloc(1024));
  float* Pfeat = (float*)(ws + alloc((size_t)NNQ * 128 * 4));
  float* Pid   = (float*)(ws + alloc((size_t)NNQ * 64 * 4));
  char*  S     = ws + alloc(166400000);
  // pool sub-buffers (phase-overlapped; lifetimes verified)
  float* itemCat  = (float*)(S + 0);          // NI x 192
  float* userCat  = (float*)(S + 23040000);   // NU x 192
  float* itemProp = (float*)(S + 38400000);   // NI x 192
  float* userProp = (float*)(S + 61440000);   // NU x 192
  float* itemV    = (float*)(S + 0);          // NI x 64   (after itemCat dead)
  float* itemT    = (float*)(S + 7680000);    // NI x 64
  float* egoF     = (float*)(S + 76800000);   // NN x 128
  float* egoId    = (float*)(S + 102400000);  // NN x 64
  float* x1       = (float*)(S + 0);          // NN x 128
  float* x2       = (float*)(S + 25600000);   // NN x 128
  float* y1       = (float*)(S + 51200000);   // NN x 64
  float* y2       = (float*)(S + 64000000);   // NN x 64
  float* tAll     = (float*)(S + 0);          // NN x 64
  float* hAll     = (float*)(S + 12800000);   // NN x 256
  float* m1All    = (float*)(S + 64000000);   // NN x 256
  float* m2All    = (float*)(S + 115200000);  // NN x 256

  // ---- phase 1: dense projections into concat buffers ----
  zero_k<<<(NIQ * 192 + 255) / 256, 256, 0, stream>>>(itemCat, NIQ * 192);
  zero_k<<<(NUQ * 192 + 255) / 256, 256, 0, stream>>>(userCat, NUQ * 192);
  copy64_k<<<(NIQ * 64 + 255) / 256, 256, 0, stream>>>(item_id_emb, 64, itemCat, 192, NIQ);
  copy64_k<<<(NUQ * 64 + 255) / 256, 256, 0, stream>>>(user_id_emb, 64, userCat, 192, NUQ);
  // trs_iv / trs_it (items), trs_uv / trs_ut (users): atomic split-K GEMMs
  gemm_k<64, 1><<<dim3(118, 2), 256, 0, stream>>>(image_feat, 2048, NIQ, img_i_w, img_i_w,
      img_i_b, img_i_b, itemCat + 64, 192, 2048, 1024, 118, NIQ, nullptr, 0, 0);
  gemm_k<64, 1><<<dim3(118, 2), 256, 0, stream>>>(text_feat, 384, NIQ, txt_i_w, txt_i_w,
      txt_i_b, txt_i_b, itemCat + 128, 192, 384, 192, 118, NIQ, nullptr, 0, 0);
  gemm_k<64, 1><<<dim3(79, 3), 256, 0, stream>>>(user_v_pref, 2048, NUQ, img_u_w, img_u_w,
      img_u_b, img_u_b, userCat + 64, 192, 2048, 704, 79, NUQ, nullptr, 0, 0);
  gemm_k<64, 1><<<dim3(79, 3), 256, 0, stream>>>(user_t_pref, 384, NUQ, txt_u_w, txt_u_w,
      txt_u_b, txt_u_b, userCat + 128, 192, 384, 128, 79, NUQ, nullptr, 0, 0);

  // ---- phase 2: CSR builds ----
  auto buildCSR = [&](const int* row, const int* col, const float* val, int n, int nnz,
                      int* P, int* C, int* CC, float* CV){
    izero_k<<<(n + 1 + 255) / 256, 256, 0, stream>>>(P, n + 1);
    count_k<<<(nnz + 255) / 256, 256, 0, stream>>>(row, nnz, P + 1);
    int n1 = n + 1;
    int nb = (n1 + 1023) / 1024;
    scan_chunk<<<nb, 256, 0, stream>>>(P, n1, bsums);
    scan_tops<<<1, 64, 0, stream>>>(bsums, nb);
    scan_add<<<nb, 256, 0, stream>>>(P, n1, bsums);
    copyi_k<<<(n + 255) / 256, 256, 0, stream>>>(P, C, n);
    fill_k<<<(nnz + 255) / 256, 256, 0, stream>>>(row, col, val, nnz, C, CC, CV);
  };
  buildCSR(ii_row, ii_col, ii_val, NIQ, NNZ_IIQ, iiP, iiC, iiColA, iiValA);
  buildCSR(uu_row, uu_col, uu_val, NUQ, NNZ_UUQ, uuP, uuC, uuColA, uuValA);
  buildCSR(adj_row, adj_col, adj_val, NNQ, NNZ_ADJQ, adjP, adjC, adjCol, adjVal);

  // ---- phase 3: ii/uu propagate + l2norm ----
  spmm_k<3><<<(NIQ * 64 + 255) / 256, 256, 0, stream>>>(iiP, iiColA, iiValA, itemCat, itemProp, NIQ, 1);
  spmm_k<3><<<(NUQ * 64 + 255) / 256, 256, 0, stream>>>(uuP, uuColA, uuValA, userCat, userProp, NUQ, 1);

  // ---- phase 4: item attention chain + ego assembly ----
  int gI = (NIQ * 64 + 255) / 256;
  attn_k<<<gI, 256, 0, stream>>>(itemProp + 64, 192, itemProp + 64, 192, itemProp + 64, 192,
      attn_in_w, attn_in_b, 0, attn_out_w, attn_out_b, ln_gamma, ln_beta, prl_alpha, itemV, 64, NIQ);
  attn_k<<<gI, 256, 0, stream>>>(itemProp + 128, 192, itemProp + 128, 192, itemProp + 128, 192,
      attn_in_w, attn_in_b, 1, attn_out_w, attn_out_b, ln_gamma, ln_beta, prl_alpha, itemT, 64, NIQ);
  copy64_k<<<(NUQ * 64 + 255) / 256, 256, 0, stream>>>(userProp, 192, egoId, 64, NUQ);
  copy64_k<<<(NIQ * 64 + 255) / 256, 256, 0, stream>>>(itemProp, 192, egoId + (size_t)NUQ * 64, 64, NIQ);
  ego_user_k<<<(NUQ * 64 + 255) / 256, 256, 0, stream>>>(userProp, prl_alpha, egoF, NUQ);
  attn_k<<<gI, 256, 0, stream>>>(itemT, 64, itemV, 64, itemV, 64,
      attn_in_w, attn_in_b, 2, attn_out_w, attn_out_b, ln_gamma, ln_beta, prl_alpha,
      egoF + (size_t)NUQ * 128, 128, NIQ);
  attn_k<<<gI, 256, 0, stream>>>(itemV, 64, itemT, 64, itemT, 64,
      attn_in_w, attn_in_b, 3, attn_out_w, attn_out_b, ln_gamma, ln_beta, prl_alpha,
      egoF + (size_t)NUQ * 128 + 64, 128, NIQ);

  // ---- phase 5: adjacency propagates (2 layers, mean of x0,x1,x2) ----
  int gN = (NNQ * 64 + 255) / 256;
  spmm_k<2><<<gN, 256, 0, stream>>>(adjP, adjCol, adjVal, egoF, x1, NNQ, 0);
  spmm_k<2><<<gN, 256, 0, stream>>>(adjP, adjCol, adjVal, x1, x2, NNQ, 0);
  mean3_k<<<(NNQ * 128 + 255) / 256, 256, 0, stream>>>(egoF, x1, x2, Pfeat, NNQ * 128);
  spmm_k<1><<<gN, 256, 0, stream>>>(adjP, adjCol, adjVal, egoId, y1, NNQ, 0);
  spmm_k<1><<<gN, 256, 0, stream>>>(adjP, adjCol, adjVal, y1, y2, NNQ, 0);
  mean3_k<<<(NNQ * 64 + 255) / 256, 256, 0, stream>>>(egoId, y1, y2, Pid, NNQ * 64);

  // ---- phase 6: meta linear (users/items combined) ----
  gemm_k<64, 0><<<dim3(197, 1), 256, 0, stream>>>(Pfeat, 128, NNQ, meta_u_w, meta_i_w,
      meta_u_b, meta_i_b, tAll, 64, 128, 128, 79, NUQ, nullptr, 0, 0);

  // ---- phase 7: MLP towers (m1 then m2), users/items combined per launch ----
  const float* pw = mlp_pre_w; const float* pb = mlp_pre_b;
  const float* ow = mlp_out_w; const float* ob = mlp_out_b;
  // m1: groups (0 users, 2 items)
  gemm_k<256, 2><<<dim3(782, 1), 256, 0, stream>>>(tAll, 64, NNQ, pw + 0 * 16384, pw + 2 * 16384,
      pb + 0 * 256, pb + 2 * 256, hAll, 256, 64, 64, 313, NUQ, mlp_alpha, 0, 2);
  gemm_k<256, 3><<<dim3(782, 1), 256, 0, stream>>>(hAll, 256, NNQ, ow + 0 * 65536, ow + 2 * 65536,
      ob + 0 * 256, ob + 2 * 256, m1All, 256, 256, 256, 313, NUQ, nullptr, 0, 0);
  // m2: groups (1 users, 3 items)
  gemm_k<256, 2><<<dim3(782, 1), 256, 0, stream>>>(tAll, 64, NNQ, pw + 1 * 16384, pw + 3 * 16384,
      pb + 1 * 256, pb + 3 * 256, hAll, 256, 64, 64, 313, NUQ, mlp_alpha, 1, 3);
  gemm_k<256, 3><<<dim3(782, 1), 256, 0, stream>>>(hAll, 256, NNQ, ow + 1 * 65536, ow + 3 * 65536,
      ob + 1 * 256, ob + 3 * 256, m2All, 256, 256, 256, 313, NUQ, nullptr, 0, 0);

  // ---- phase 8: share einsum + final assembly ----
  final_k<<<gN, 256, 0, stream>>>(Pfeat, Pid, m1All, m2All, prl_alpha, out, NNQ);
}